// Round 5
// baseline (108.389 us; speedup 1.0000x reference)
//
#include <hip/hip_runtime.h>

typedef float f32x4 __attribute__((ext_vector_type(4)));
typedef __bf16 bf16x8 __attribute__((ext_vector_type(8)));
typedef unsigned short u16;
typedef unsigned int u32;

__device__ __forceinline__ float bf2f(u32 b) {
  u32 x = (b & 0xffffu) << 16;
  return __builtin_bit_cast(float, x);
}
__device__ __forceinline__ u16 f2bf(float f) {
  u32 x = __builtin_bit_cast(u32, f);
  x += 0x7fffu + ((x >> 16) & 1u);
  return (u16)(x >> 16);
}
__device__ __forceinline__ void gload16(const void* g, void* l) {
  __builtin_amdgcn_global_load_lds((__attribute__((address_space(1))) void*)g,
                                   (__attribute__((address_space(3))) void*)l,
                                   16, 0, 0);
}
// XCD-aware chunked bijective block remap (grid must be a multiple of 8).
__device__ __forceinline__ int xcd_swz(int bid, int nwg) {
  int per = nwg >> 3;
  return (bid & 7) * per + (bid >> 3);
}

// ---- LN over channels of BCHW + transpose to (n,c) bf16, + fused prep ------
__global__ __launch_bounds__(256, 2)
void k_ln2d_prep(const float* __restrict__ x, const float* __restrict__ lw,
                 const float* __restrict__ lb, u16* __restrict__ A,
                 const float* __restrict__ inproj_w, const float* __restrict__ ssm_in_w,
                 const float* __restrict__ ssm_out_w, const float* __restrict__ outproj_w,
                 const float* __restrict__ dw2d_w, const float* __restrict__ ssm_dw_w,
                 const float* __restrict__ ssm_dw_b, const float* __restrict__ ssm_out_b,
                 u16* __restrict__ w1b, u16* __restrict__ w2b, u16* __restrict__ w3b,
                 u16* __restrict__ w4b, float* __restrict__ cvec, float* __restrict__ wT9,
                 float* __restrict__ w02, float* __restrict__ w14) {
  __shared__ float T[256 * 65];
  __shared__ float ps1[4][64], ps2[4][64];
  __shared__ float mu[64], rsd[64];
  int bid = blockIdx.x, tid = threadIdx.x;
  if (bid >= 256) {
    int pb = bid - 256;
    if (pb < 512) {
      const float* s; u16* d; int base;
      if (pb < 256)      { s = ssm_in_w;  d = w2b; base = pb; }
      else if (pb < 384) { s = ssm_out_w; d = w3b; base = pb - 256; }
      else if (pb < 448) { s = inproj_w;  d = w1b; base = pb - 384; }
      else               { s = outproj_w; d = w4b; base = pb - 448; }
      int i = base * 1024 + tid * 4;
      float4 v = *(const float4*)&s[i];
      u32 a = (u32)f2bf(v.x) | ((u32)f2bf(v.y) << 16);
      u32 b = (u32)f2bf(v.z) | ((u32)f2bf(v.w) << 16);
      *(uint2*)&d[i] = make_uint2(a, b);
    } else if (pb == 512) {
      float s = ssm_out_b[tid];
      const float* wr = ssm_out_w + (size_t)tid * 512;
      #pragma unroll 8
      for (int k = 0; k < 512; ++k) s += ssm_dw_b[k] * wr[k];
      cvec[tid] = s;
    } else {
      #pragma unroll
      for (int j = 0; j < 9; ++j) wT9[j * 256 + tid] = dw2d_w[tid * 9 + j];
      #pragma unroll
      for (int q = 0; q < 2; ++q) {
        int c = tid + q * 256;
        w02[c] = ssm_dw_w[c * 3 + 0] + ssm_dw_w[c * 3 + 2];
        w14[c] = 4.f * ssm_dw_w[c * 3 + 1];
      }
    }
    return;
  }
  int wv = tid >> 6, lane = tid & 63;
  int cq = lane >> 4, p4 = (lane & 15) * 4;
  int n0 = bid * 64, bb = n0 >> 12, hw0 = n0 & 4095;
  const float* xb = x + ((size_t)bb << 20);
  float s0 = 0, s1 = 0, s2 = 0, s3 = 0;
  float q0 = 0, q1 = 0, q2 = 0, q3 = 0;
  #pragma unroll 4
  for (int i = 0; i < 16; ++i) {
    int c = wv * 64 + i * 4 + cq;
    float4 v = *(const float4*)&xb[((size_t)c << 12) + hw0 + p4];
    T[c * 65 + p4 + 0] = v.x; T[c * 65 + p4 + 1] = v.y;
    T[c * 65 + p4 + 2] = v.z; T[c * 65 + p4 + 3] = v.w;
    s0 += v.x; s1 += v.y; s2 += v.z; s3 += v.w;
    q0 += v.x * v.x; q1 += v.y * v.y; q2 += v.z * v.z; q3 += v.w * v.w;
  }
  #pragma unroll
  for (int off = 16; off < 64; off <<= 1) {
    s0 += __shfl_xor(s0, off); s1 += __shfl_xor(s1, off);
    s2 += __shfl_xor(s2, off); s3 += __shfl_xor(s3, off);
    q0 += __shfl_xor(q0, off); q1 += __shfl_xor(q1, off);
    q2 += __shfl_xor(q2, off); q3 += __shfl_xor(q3, off);
  }
  if (cq == 0) {
    ps1[wv][p4 + 0] = s0; ps1[wv][p4 + 1] = s1; ps1[wv][p4 + 2] = s2; ps1[wv][p4 + 3] = s3;
    ps2[wv][p4 + 0] = q0; ps2[wv][p4 + 1] = q1; ps2[wv][p4 + 2] = q2; ps2[wv][p4 + 3] = q3;
  }
  __syncthreads();
  if (tid < 64) {
    float S1 = ps1[0][tid] + ps1[1][tid] + ps1[2][tid] + ps1[3][tid];
    float S2 = ps2[0][tid] + ps2[1][tid] + ps2[2][tid] + ps2[3][tid];
    float m = S1 * (1.f / 256.f);
    float var = S2 * (1.f / 256.f) - m * m;
    mu[tid] = m;
    rsd[tid] = rsqrtf(var + 1e-6f);
  }
  __syncthreads();
  int c4b = (tid & 15) * 4, p2b = tid >> 4;
  #pragma unroll
  for (int cc = 0; cc < 4; ++cc) {
    int c4 = cc * 64 + c4b;
    float4 w4 = *(const float4*)&lw[c4];
    float4 g4 = *(const float4*)&lb[c4];
    #pragma unroll
    for (int i2 = 0; i2 < 4; ++i2) {
      int p2 = p2b + 16 * i2;
      float m = mu[p2], rs = rsd[p2];
      float o0 = (T[(c4 + 0) * 65 + p2] - m) * rs * w4.x + g4.x;
      float o1 = (T[(c4 + 1) * 65 + p2] - m) * rs * w4.y + g4.y;
      float o2 = (T[(c4 + 2) * 65 + p2] - m) * rs * w4.z + g4.z;
      float o3 = (T[(c4 + 3) * 65 + p2] - m) * rs * w4.w + g4.w;
      u32 a = (u32)f2bf(o0) | ((u32)f2bf(o1) << 16);
      u32 b = (u32)f2bf(o2) | ((u32)f2bf(o3) << 16);
      *(uint2*)&A[(size_t)(n0 + p2) * 256 + c4] = make_uint2(a, b);
    }
  }
}

// -------- depthwise 3x3 + fused row-LN: Yc = conv(Y1), A = LN(Yc) ----------
__global__ __launch_bounds__(256)
void k_dw3x3_ln(const u16* __restrict__ Y1, const float* __restrict__ wT,
                const float* __restrict__ dwb, const float* __restrict__ lnw,
                const float* __restrict__ lnb, u16* __restrict__ Yc,
                u16* __restrict__ A) {
  int tid = threadIdx.x;
  int wg = xcd_swz(blockIdx.x, 4096);
  int n = wg * 4 + (tid >> 6);
  int lane = tid & 63;
  int c0 = lane * 4;
  int b = n >> 12, hw = n & 4095, h = hw >> 6, w = hw & 63;
  float4 b4 = *(const float4*)&dwb[c0];
  float a0 = b4.x, a1 = b4.y, a2 = b4.z, a3 = b4.w;
  #pragma unroll
  for (int ky = 0; ky < 3; ++ky) {
    int hh = h + ky - 1;
    if (hh < 0 || hh > 63) continue;
    #pragma unroll
    for (int kx = 0; kx < 3; ++kx) {
      int ww = w + kx - 1;
      if (ww < 0 || ww > 63) continue;
      size_t nn = ((size_t)b << 12) + (hh << 6) + ww;
      uint2 u = *(const uint2*)&Y1[nn * 256 + c0];
      float4 w4 = *(const float4*)&wT[(ky * 3 + kx) * 256 + c0];
      a0 += bf2f(u.x) * w4.x;
      a1 += bf2f(u.x >> 16) * w4.y;
      a2 += bf2f(u.y) * w4.z;
      a3 += bf2f(u.y >> 16) * w4.w;
    }
  }
  u32 p0 = (u32)f2bf(a0) | ((u32)f2bf(a1) << 16);
  u32 p1 = (u32)f2bf(a2) | ((u32)f2bf(a3) << 16);
  *(uint2*)&Yc[(size_t)n * 256 + c0] = make_uint2(p0, p1);
  float s1 = a0 + a1 + a2 + a3;
  float s2 = a0 * a0 + a1 * a1 + a2 * a2 + a3 * a3;
  #pragma unroll
  for (int off = 1; off < 64; off <<= 1) {
    s1 += __shfl_xor(s1, off);
    s2 += __shfl_xor(s2, off);
  }
  float m = s1 * (1.f / 256.f);
  float var = s2 * (1.f / 256.f) - m * m;
  float rs = rsqrtf(var + 1e-6f);
  float4 w4 = *(const float4*)&lnw[c0];
  float4 g4 = *(const float4*)&lnb[c0];
  float o0 = (a0 - m) * rs * w4.x + g4.x;
  float o1 = (a1 - m) * rs * w4.y + g4.y;
  float o2 = (a2 - m) * rs * w4.z + g4.z;
  float o3 = (a3 - m) * rs * w4.w + g4.w;
  u32 qa = (u32)f2bf(o0) | ((u32)f2bf(o1) << 16);
  u32 qb = (u32)f2bf(o2) | ((u32)f2bf(o3) << 16);
  *(uint2*)&A[(size_t)n * 256 + c0] = make_uint2(qa, qb);
}

// ------- MFMA GEMM, 64x128 tile, BK=32, 2-phase double-buffered pipeline -----
// EPI 0: outb[r*ldo+c] = bf16(acc + bias[c])                      (R=A, C=W)
// EPI 2: R=W (rows=o), C=A (cols=n); outf[(b*256+o)*4096+hw] = acc+bias[o]+resf
// RFAST: rt varies fastest in the swizzled id (blocks sharing a C-panel pack
// into one XCD chunk).
template <int EPI, int NCT, bool RFAST>
__global__ __launch_bounds__(256, 4)
void k_gemm2(const u16* __restrict__ R, const u16* __restrict__ Cm,
             const float* __restrict__ bias, int K, int ldo,
             u16* __restrict__ outb, float* __restrict__ outf,
             const float* __restrict__ resf) {
  __shared__ u16 tR[2][64 * 32];
  __shared__ u16 tC[2][128 * 32];
  int tid = threadIdx.x, lane = tid & 63, wv = tid >> 6;
  int wg = xcd_swz(blockIdx.x, gridDim.x);
  int nRt = gridDim.x / NCT;
  int rt = RFAST ? (wg % nRt) : (wg / NCT);
  int ct = RFAST ? (wg / nRt) : (wg % NCT);
  int r0 = rt * 64, c0 = ct * 128;
  int fr = lane & 15, kc = lane >> 4;
  int sr = lane >> 2, sc = (lane & 3) * 8;
  f32x4 acc[4][2] = {};
  int nK = K >> 5;
  const u16* gR  = R  + (size_t)(r0 + wv * 16 + sr) * K + sc;
  const u16* gC0 = Cm + (size_t)(c0 + wv * 32 + sr) * K + sc;
  const u16* gC1 = Cm + (size_t)(c0 + wv * 32 + 16 + sr) * K + sc;
  auto STAGE = [&](int buf, int kt) {
    int k0 = kt * 32;
    gload16(gR + k0,  &tR[buf][wv * 16 * 32]);
    gload16(gC0 + k0, &tC[buf][(wv * 32) * 32]);
    gload16(gC1 + k0, &tC[buf][(wv * 32 + 16) * 32]);
  };
  auto COMPUTE = [&](int buf) {
    bf16x8 af[4], wf[2];
    #pragma unroll
    for (int m = 0; m < 4; ++m)
      af[m] = *(const bf16x8*)&tR[buf][(m * 16 + fr) * 32 + kc * 8];
    #pragma unroll
    for (int n = 0; n < 2; ++n)
      wf[n] = *(const bf16x8*)&tC[buf][(wv * 32 + n * 16 + fr) * 32 + kc * 8];
    #pragma unroll
    for (int m = 0; m < 4; ++m)
      #pragma unroll
      for (int n = 0; n < 2; ++n)
        acc[m][n] = __builtin_amdgcn_mfma_f32_16x16x32_bf16(af[m], wf[n], acc[m][n], 0, 0, 0);
  };
  STAGE(0, 0);
  __syncthreads();
  int cur = 0;
  for (int kt = 0; kt < nK - 1; ++kt) {
    STAGE(cur ^ 1, kt + 1);
    __builtin_amdgcn_sched_barrier(0);
    COMPUTE(cur);
    __syncthreads();
    cur ^= 1;
  }
  COMPUTE(cur);
  #pragma unroll
  for (int m = 0; m < 4; ++m) {
    #pragma unroll
    for (int n = 0; n < 2; ++n) {
      #pragma unroll
      for (int r = 0; r < 4; ++r) {
        float v = acc[m][n][r];
        if (EPI == 0) {
          int gn = r0 + m * 16 + kc * 4 + r;
          int go = c0 + wv * 32 + n * 16 + fr;
          outb[(size_t)gn * ldo + go] = f2bf(v + bias[go]);
        } else {
          int go = r0 + m * 16 + kc * 4 + r;           // output channel
          int gn = c0 + wv * 32 + n * 16 + fr;         // position
          int b = gn >> 12, hw = gn & 4095;
          size_t idx = (((size_t)(b * 256 + go)) << 12) + hw;
          float res = __builtin_nontemporal_load(&resf[idx]);
          __builtin_nontemporal_store(v + bias[go] + res, &outf[idx]);
        }
      }
    }
  }
}

// ------- fused ssm_in GEMM + SiLU gate, 128x128 tile (a+g panels) ----------
__global__ __launch_bounds__(256, 2)
void k_gate2(const u16* __restrict__ A, const u16* __restrict__ W,
             const float* __restrict__ bias, u16* __restrict__ G) {
  __shared__ u16 tR[2][128 * 32];
  __shared__ u16 tCa[2][128 * 32];
  __shared__ u16 tCg[2][128 * 32];
  int tid = threadIdx.x, lane = tid & 63, wv = tid >> 6;
  int wg = xcd_swz(blockIdx.x, 512);
  int rt = wg >> 2, ot = wg & 3;
  int r0 = rt * 128, o0 = ot * 128;
  int wr = wv >> 1, wc = wv & 1;
  int fr = lane & 15, kc = lane >> 4;
  const int K = 256;
  f32x4 acca[4][4] = {}, accg[4][4] = {};
  auto STAGE = [&](int buf, int kt) {
    int k0 = kt * 32;
    #pragma unroll
    for (int i = 0; i < 2; ++i) {
      int s0 = wv * 128 + i * 64;
      int s = s0 + lane;
      int row = s >> 2, off = (s & 3) * 8;
      gload16(A + (size_t)(r0 + row) * K + k0 + off, &tR[buf][s0 * 8]);
      gload16(W + (size_t)(o0 + row) * K + k0 + off, &tCa[buf][s0 * 8]);
      gload16(W + (size_t)(512 + o0 + row) * K + k0 + off, &tCg[buf][s0 * 8]);
    }
  };
  auto COMPUTE = [&](int buf) {
    bf16x8 af[4], wa[4], wgf[4];
    #pragma unroll
    for (int m = 0; m < 4; ++m)
      af[m] = *(const bf16x8*)&tR[buf][(wr * 64 + m * 16 + fr) * 32 + kc * 8];
    #pragma unroll
    for (int n = 0; n < 4; ++n) {
      wa[n]  = *(const bf16x8*)&tCa[buf][(wc * 64 + n * 16 + fr) * 32 + kc * 8];
      wgf[n] = *(const bf16x8*)&tCg[buf][(wc * 64 + n * 16 + fr) * 32 + kc * 8];
    }
    #pragma unroll
    for (int m = 0; m < 4; ++m)
      #pragma unroll
      for (int n = 0; n < 4; ++n) {
        acca[m][n] = __builtin_amdgcn_mfma_f32_16x16x32_bf16(af[m], wa[n], acca[m][n], 0, 0, 0);
        accg[m][n] = __builtin_amdgcn_mfma_f32_16x16x32_bf16(af[m], wgf[n], accg[m][n], 0, 0, 0);
      }
  };
  STAGE(0, 0);
  __syncthreads();
  int cur = 0;
  for (int kt = 0; kt < 7; ++kt) {
    STAGE(cur ^ 1, kt + 1);
    __builtin_amdgcn_sched_barrier(0);
    COMPUTE(cur);
    __syncthreads();
    cur ^= 1;
  }
  COMPUTE(cur);
  #pragma unroll
  for (int m = 0; m < 4; ++m) {
    #pragma unroll
    for (int n = 0; n < 4; ++n) {
      #pragma unroll
      for (int r = 0; r < 4; ++r) {
        int gn = r0 + wr * 64 + m * 16 + kc * 4 + r;
        int go = o0 + wc * 64 + n * 16 + fr;
        float a = acca[m][n][r] + bias[go];
        float g = accg[m][n][r] + bias[512 + go];
        G[(size_t)gn * 512 + go] = f2bf(a / (1.f + expf(-g)));
      }
    }
  }
}

// ------- fused 4-dir conv1d + ssm_out GEMM -----------------------------------
// R rows = Z[n,k] computed on the fly from G (5-pt stencil); C = W3 (256x512).
// Tile 32 rows x 256 cols, grid 512, K=512 (16 steps of 32).
__global__ __launch_bounds__(256, 2)
void k_gemm_scan(const u16* __restrict__ G, const u16* __restrict__ W3,
                 const float* __restrict__ w02, const float* __restrict__ w14,
                 const float* __restrict__ cvec, const u16* __restrict__ Yc,
                 u16* __restrict__ M) {
  __shared__ u16 tR[2][32 * 32];
  __shared__ u16 tC[2][256 * 32];
  int tid = threadIdx.x, lane = tid & 63, wv = tid >> 6;
  int wg = xcd_swz(blockIdx.x, 512);
  int r0 = wg * 32;
  int fr = lane & 15, kc = lane >> 4;
  int zrow = tid >> 3;            // 0..31
  int zg = (tid & 7) * 4;         // channel-group within the 32-wide K slice
  int n = r0 + zrow;
  int b = n >> 12, hw = n & 4095, h = hw >> 6, w = hw & 63;
  int m = w * 64 + h;
  int mm1 = m - 1, mp1 = m + 1;
  size_t o_c = (size_t)n * 512 + zg;
  size_t o_p = (size_t)(hw > 0 ? n - 1 : n) * 512 + zg;
  size_t o_n = (size_t)(hw < 4095 ? n + 1 : n) * 512 + zg;
  size_t o_u = (size_t)(m > 0 ? ((b << 12) + ((mm1 & 63) << 6) + (mm1 >> 6)) : n) * 512 + zg;
  size_t o_d = (size_t)(m < 4095 ? ((b << 12) + ((mp1 & 63) << 6) + (mp1 >> 6)) : n) * 512 + zg;
  float mP = hw > 0 ? 1.f : 0.f, mN = hw < 4095 ? 1.f : 0.f;
  float mU = m > 0 ? 1.f : 0.f, mD = m < 4095 ? 1.f : 0.f;
  f32x4 acc[2][4] = {};
  auto STAGE_C = [&](int buf, int kt) {
    int k0 = kt * 32;
    #pragma unroll
    for (int i = 0; i < 4; ++i) {
      int s0 = wv * 256 + i * 64;        // wave-uniform lane-slot base
      int s = s0 + lane;
      int row = s >> 2, off = (s & 3) * 8;
      gload16(W3 + (size_t)row * 512 + k0 + off, &tC[buf][s0 * 8]);
    }
  };
  uint2 lc, lp, ln_, lu, ld;
  float4 va, vb;
  auto ZLOAD = [&](int kt) {
    int c = kt * 32 + zg;
    lc  = *(const uint2*)&G[o_c + (kt * 32)];
    lp  = *(const uint2*)&G[o_p + (kt * 32)];
    ln_ = *(const uint2*)&G[o_n + (kt * 32)];
    lu  = *(const uint2*)&G[o_u + (kt * 32)];
    ld  = *(const uint2*)&G[o_d + (kt * 32)];
    va = *(const float4*)&w02[c];
    vb = *(const float4*)&w14[c];
  };
  auto ZSTORE = [&](int buf) {
    float s_0 = mP * bf2f(lp.x) + mN * bf2f(ln_.x) + mU * bf2f(lu.x) + mD * bf2f(ld.x);
    float s_1 = mP * bf2f(lp.x >> 16) + mN * bf2f(ln_.x >> 16) + mU * bf2f(lu.x >> 16) + mD * bf2f(ld.x >> 16);
    float s_2 = mP * bf2f(lp.y) + mN * bf2f(ln_.y) + mU * bf2f(lu.y) + mD * bf2f(ld.y);
    float s_3 = mP * bf2f(lp.y >> 16) + mN * bf2f(ln_.y >> 16) + mU * bf2f(lu.y >> 16) + mD * bf2f(ld.y >> 16);
    float z0 = va.x * s_0 + vb.x * bf2f(lc.x);
    float z1 = va.y * s_1 + vb.y * bf2f(lc.x >> 16);
    float z2 = va.z * s_2 + vb.z * bf2f(lc.y);
    float z3 = va.w * s_3 + vb.w * bf2f(lc.y >> 16);
    u32 p0 = (u32)f2bf(z0) | ((u32)f2bf(z1) << 16);
    u32 p1 = (u32)f2bf(z2) | ((u32)f2bf(z3) << 16);
    *(uint2*)&tR[buf][zrow * 32 + zg] = make_uint2(p0, p1);
  };
  auto COMPUTE = [&](int buf) {
    bf16x8 af[2], wf[4];
    #pragma unroll
    for (int mi = 0; mi < 2; ++mi)
      af[mi] = *(const bf16x8*)&tR[buf][(mi * 16 + fr) * 32 + kc * 8];
    #pragma unroll
    for (int ni = 0; ni < 4; ++ni)
      wf[ni] = *(const bf16x8*)&tC[buf][(wv * 64 + ni * 16 + fr) * 32 + kc * 8];
    #pragma unroll
    for (int mi = 0; mi < 2; ++mi)
      #pragma unroll
      for (int ni = 0; ni < 4; ++ni)
        acc[mi][ni] = __builtin_amdgcn_mfma_f32_16x16x32_bf16(af[mi], wf[ni], acc[mi][ni], 0, 0, 0);
  };
  STAGE_C(0, 0);
  ZLOAD(0);
  ZSTORE(0);
  __syncthreads();
  int cur = 0;
  for (int kt = 0; kt < 15; ++kt) {
    ZLOAD(kt + 1);              // issue early (T14): hidden under MFMA
    STAGE_C(cur ^ 1, kt + 1);
    COMPUTE(cur);
    ZSTORE(cur ^ 1);            // vmcnt-wait lands after the MFMA cluster
    __syncthreads();
    cur ^= 1;
  }
  COMPUTE(cur);
  #pragma unroll
  for (int mi = 0; mi < 2; ++mi) {
    #pragma unroll
    for (int ni = 0; ni < 4; ++ni) {
      #pragma unroll
      for (int r = 0; r < 4; ++r) {
        int gn = r0 + mi * 16 + kc * 4 + r;
        int go = wv * 64 + ni * 16 + fr;
        size_t idx = (size_t)gn * 256 + go;
        M[idx] = f2bf(0.25f * acc[mi][ni][r] + cvec[go] + bf2f(Yc[idx]));
      }
    }
  }
}

extern "C" void kernel_launch(void* const* d_in, const int* in_sizes, int n_in,
                              void* d_out, int out_size, void* d_ws, size_t ws_size,
                              hipStream_t stream) {
  const float* x         = (const float*)d_in[0];
  const float* ln2d_w    = (const float*)d_in[1];
  const float* ln2d_b    = (const float*)d_in[2];
  const float* inproj_w  = (const float*)d_in[3];
  const float* inproj_b  = (const float*)d_in[4];
  const float* dw2d_w    = (const float*)d_in[5];
  const float* dw2d_b    = (const float*)d_in[6];
  const float* ssm_ln_w  = (const float*)d_in[7];
  const float* ssm_ln_b  = (const float*)d_in[8];
  const float* ssm_in_w  = (const float*)d_in[9];
  const float* ssm_in_b  = (const float*)d_in[10];
  const float* ssm_dw_w  = (const float*)d_in[11];
  const float* ssm_dw_b  = (const float*)d_in[12];
  const float* ssm_out_w = (const float*)d_in[13];
  const float* ssm_out_b = (const float*)d_in[14];
  const float* outproj_w = (const float*)d_in[15];
  const float* outproj_b = (const float*)d_in[16];
  float* out = (float*)d_out;

  char* ws = (char*)d_ws;
  size_t off = 0;
  auto take = [&](size_t bytes) -> char* {
    char* p = ws + off;
    off = (off + bytes + 255) & ~(size_t)255;
    return p;
  };
  u16* w1b    = (u16*)take(65536 * 2);
  u16* w2b    = (u16*)take(262144 * 2);
  u16* w3b    = (u16*)take(131072 * 2);
  u16* w4b    = (u16*)take(65536 * 2);
  float* cvec = (float*)take(256 * 4);
  float* wT9  = (float*)take(9 * 256 * 4);
  float* w02  = (float*)take(512 * 4);
  float* w14  = (float*)take(512 * 4);
  u16* Abuf   = (u16*)take((size_t)16384 * 256 * 2); // A1 -> A2 -> M (serial reuse)
  u16* Y1     = (u16*)take((size_t)16384 * 256 * 2);
  u16* Yc     = (u16*)take((size_t)16384 * 256 * 2);
  u16* G      = (u16*)take((size_t)16384 * 512 * 2);
  (void)ws_size; (void)in_sizes; (void)n_in; (void)out_size;

  // 1) LN over channels + transpose to (n,c); fused weight prep (extra blocks)
  k_ln2d_prep<<<770, 256, 0, stream>>>(x, ln2d_w, ln2d_b, Abuf,
                                       inproj_w, ssm_in_w, ssm_out_w, outproj_w,
                                       dw2d_w, ssm_dw_w, ssm_dw_b, ssm_out_b,
                                       w1b, w2b, w3b, w4b, cvec, wT9, w02, w14);
  // 2) inproj GEMM
  k_gemm2<0, 2, false><<<512, 256, 0, stream>>>(Abuf, w1b, inproj_b, 256, 256,
                                                Y1, nullptr, nullptr);
  // 3) depthwise 3x3 + fused ssm LN
  k_dw3x3_ln<<<4096, 256, 0, stream>>>(Y1, wT9, dw2d_b, ssm_ln_w, ssm_ln_b, Yc, Abuf);
  // 4) ssm_in GEMM + SiLU gate (128x128 tile)
  k_gate2<<<512, 256, 0, stream>>>(Abuf, w2b, ssm_in_b, G);
  // 5) fused 4-dir conv1d + ssm_out GEMM: M = 0.25*Z@Wout^T + cvec + Yc
  k_gemm_scan<<<512, 256, 0, stream>>>(G, w3b, w02, w14, cvec, Yc, Abuf);
  // 6) outproj GEMM (o-rows staged, position-cols) + x residual, f32 out
  k_gemm2<2, 128, true><<<512, 256, 0, stream>>>(w4b, Abuf, outproj_b, 256, 0,
                                                 nullptr, out, x);
}

// Round 6
// 105.928 us; speedup vs baseline: 1.0232x; 1.0232x over previous
//
#include <hip/hip_runtime.h>

typedef float f32x4 __attribute__((ext_vector_type(4)));
typedef __bf16 bf16x8 __attribute__((ext_vector_type(8)));
typedef unsigned short u16;
typedef unsigned int u32;

__device__ __forceinline__ float bf2f(u32 b) {
  u32 x = (b & 0xffffu) << 16;
  return __builtin_bit_cast(float, x);
}
__device__ __forceinline__ u16 f2bf(float f) {
  u32 x = __builtin_bit_cast(u32, f);
  x += 0x7fffu + ((x >> 16) & 1u);
  return (u16)(x >> 16);
}
__device__ __forceinline__ void gload16(const void* g, void* l) {
  __builtin_amdgcn_global_load_lds((__attribute__((address_space(1))) void*)g,
                                   (__attribute__((address_space(3))) void*)l,
                                   16, 0, 0);
}
// XCD-aware chunked bijective block remap (grid must be a multiple of 8).
__device__ __forceinline__ int xcd_swz(int bid, int nwg) {
  int per = nwg >> 3;
  return (bid & 7) * per + (bid >> 3);
}
// 8 consecutive f32 -> bf16x8 (RNE, same rounding as f2bf prep path)
__device__ __forceinline__ bf16x8 cvt8(const float* __restrict__ p) {
  float4 lo = *(const float4*)p;
  float4 hi = *(const float4*)(p + 4);
  union { u16 e[8]; bf16x8 v; } u;
  u.e[0] = f2bf(lo.x); u.e[1] = f2bf(lo.y); u.e[2] = f2bf(lo.z); u.e[3] = f2bf(lo.w);
  u.e[4] = f2bf(hi.x); u.e[5] = f2bf(hi.y); u.e[6] = f2bf(hi.z); u.e[7] = f2bf(hi.w);
  return u.v;
}

// ---- FUSED: LN over channels + inproj GEMM -> Y1; prep blocks ride along ---
// Blocks 0..255: LN(64 positions x 256 ch) into LDS, then Y1 = A @ W1^T.
// Blocks 256..705: weight prep (w2b/w3b/w4b bf16 conversion, cvec, dw folds).
__global__ __launch_bounds__(256)
void k_lnproj(const float* __restrict__ x, const float* __restrict__ lw,
              const float* __restrict__ lb, const float* __restrict__ W1,
              const float* __restrict__ inproj_b, u16* __restrict__ Y1,
              const float* __restrict__ ssm_in_w, const float* __restrict__ ssm_out_w,
              const float* __restrict__ outproj_w, const float* __restrict__ dw2d_w,
              const float* __restrict__ ssm_dw_w, const float* __restrict__ ssm_dw_b,
              const float* __restrict__ ssm_out_b,
              u16* __restrict__ w2b, u16* __restrict__ w3b, u16* __restrict__ w4b,
              float* __restrict__ cvec, float* __restrict__ wT9,
              float* __restrict__ w02, float* __restrict__ w14) {
  __shared__ u16 sA[64 * 264];
  __shared__ float ps1[4][64], ps2[4][64];
  __shared__ float mu[64], rsd[64];
  int bid = blockIdx.x, tid = threadIdx.x;
  if (bid >= 256) {
    int pb = bid - 256;
    if (pb < 448) {
      const float* s; u16* d; int base;
      if (pb < 256)      { s = ssm_in_w;  d = w2b; base = pb; }
      else if (pb < 384) { s = ssm_out_w; d = w3b; base = pb - 256; }
      else               { s = outproj_w; d = w4b; base = pb - 384; }
      int i = base * 1024 + tid * 4;
      float4 v = *(const float4*)&s[i];
      u32 a = (u32)f2bf(v.x) | ((u32)f2bf(v.y) << 16);
      u32 b = (u32)f2bf(v.z) | ((u32)f2bf(v.w) << 16);
      *(uint2*)&d[i] = make_uint2(a, b);
    } else if (pb == 448) {
      float s = ssm_out_b[tid];
      const float* wr = ssm_out_w + (size_t)tid * 512;
      #pragma unroll 8
      for (int k = 0; k < 512; ++k) s += ssm_dw_b[k] * wr[k];
      cvec[tid] = s;
    } else {
      #pragma unroll
      for (int j = 0; j < 9; ++j) wT9[j * 256 + tid] = dw2d_w[tid * 9 + j];
      #pragma unroll
      for (int q = 0; q < 2; ++q) {
        int c = tid + q * 256;
        w02[c] = ssm_dw_w[c * 3 + 0] + ssm_dw_w[c * 3 + 2];
        w14[c] = 4.f * ssm_dw_w[c * 3 + 1];
      }
    }
    return;
  }
  int wv = tid >> 6, lane = tid & 63;
  int cq = lane >> 4, p4 = (lane & 15) * 4;
  int n0 = bid * 64, bb = n0 >> 12, hw0 = n0 & 4095;
  const float* xb = x + ((size_t)bb << 20);
  float4 xv[16];
  float s0 = 0, s1 = 0, s2 = 0, s3 = 0;
  float q0 = 0, q1 = 0, q2 = 0, q3 = 0;
  #pragma unroll
  for (int i = 0; i < 16; ++i) {
    int c = wv * 64 + i * 4 + cq;
    float4 v = *(const float4*)&xb[((size_t)c << 12) + hw0 + p4];
    xv[i] = v;
    s0 += v.x; s1 += v.y; s2 += v.z; s3 += v.w;
    q0 += v.x * v.x; q1 += v.y * v.y; q2 += v.z * v.z; q3 += v.w * v.w;
  }
  #pragma unroll
  for (int off = 16; off < 64; off <<= 1) {
    s0 += __shfl_xor(s0, off); s1 += __shfl_xor(s1, off);
    s2 += __shfl_xor(s2, off); s3 += __shfl_xor(s3, off);
    q0 += __shfl_xor(q0, off); q1 += __shfl_xor(q1, off);
    q2 += __shfl_xor(q2, off); q3 += __shfl_xor(q3, off);
  }
  if (cq == 0) {
    ps1[wv][p4 + 0] = s0; ps1[wv][p4 + 1] = s1; ps1[wv][p4 + 2] = s2; ps1[wv][p4 + 3] = s3;
    ps2[wv][p4 + 0] = q0; ps2[wv][p4 + 1] = q1; ps2[wv][p4 + 2] = q2; ps2[wv][p4 + 3] = q3;
  }
  __syncthreads();
  if (tid < 64) {
    float S1 = ps1[0][tid] + ps1[1][tid] + ps1[2][tid] + ps1[3][tid];
    float S2 = ps2[0][tid] + ps2[1][tid] + ps2[2][tid] + ps2[3][tid];
    float m = S1 * (1.f / 256.f);
    float var = S2 * (1.f / 256.f) - m * m;
    mu[tid] = m;
    rsd[tid] = rsqrtf(var + 1e-6f);
  }
  __syncthreads();
  // normalize from registers -> sA[pos][ch] bf16
  #pragma unroll
  for (int i = 0; i < 16; ++i) {
    int c = wv * 64 + i * 4 + cq;
    float wc = lw[c], bc = lb[c];
    float4 v = xv[i];
    sA[(p4 + 0) * 264 + c] = f2bf((v.x - mu[p4 + 0]) * rsd[p4 + 0] * wc + bc);
    sA[(p4 + 1) * 264 + c] = f2bf((v.y - mu[p4 + 1]) * rsd[p4 + 1] * wc + bc);
    sA[(p4 + 2) * 264 + c] = f2bf((v.z - mu[p4 + 2]) * rsd[p4 + 2] * wc + bc);
    sA[(p4 + 3) * 264 + c] = f2bf((v.w - mu[p4 + 3]) * rsd[p4 + 3] * wc + bc);
  }
  __syncthreads();
  // GEMM: D[64 pos][256 o]; wave wv owns o in [wv*64, wv*64+64)
  int fr = lane & 15, kc = lane >> 4;
  f32x4 acc[4][4] = {};
  #pragma unroll 2
  for (int kt = 0; kt < 8; ++kt) {
    bf16x8 af[4];
    #pragma unroll
    for (int m = 0; m < 4; ++m)
      af[m] = *(const bf16x8*)&sA[(m * 16 + fr) * 264 + kt * 32 + kc * 8];
    #pragma unroll
    for (int n = 0; n < 4; ++n) {
      bf16x8 wf = cvt8(W1 + (size_t)(wv * 64 + n * 16 + fr) * 256 + kt * 32 + kc * 8);
      #pragma unroll
      for (int m = 0; m < 4; ++m)
        acc[m][n] = __builtin_amdgcn_mfma_f32_16x16x32_bf16(af[m], wf, acc[m][n], 0, 0, 0);
    }
  }
  #pragma unroll
  for (int m = 0; m < 4; ++m) {
    #pragma unroll
    for (int n = 0; n < 4; ++n) {
      #pragma unroll
      for (int r = 0; r < 4; ++r) {
        int gn = n0 + m * 16 + kc * 4 + r;
        int go = wv * 64 + n * 16 + fr;
        Y1[(size_t)gn * 256 + go] = f2bf(acc[m][n][r] + inproj_b[go]);
      }
    }
  }
}

// -------- depthwise 3x3 + fused row-LN: Yc = conv(Y1), A = LN(Yc) ----------
__global__ __launch_bounds__(256)
void k_dw3x3_ln(const u16* __restrict__ Y1, const float* __restrict__ wT,
                const float* __restrict__ dwb, const float* __restrict__ lnw,
                const float* __restrict__ lnb, u16* __restrict__ Yc,
                u16* __restrict__ A) {
  int tid = threadIdx.x;
  int wg = xcd_swz(blockIdx.x, 4096);
  int n = wg * 4 + (tid >> 6);
  int lane = tid & 63;
  int c0 = lane * 4;
  int b = n >> 12, hw = n & 4095, h = hw >> 6, w = hw & 63;
  float4 b4 = *(const float4*)&dwb[c0];
  float a0 = b4.x, a1 = b4.y, a2 = b4.z, a3 = b4.w;
  #pragma unroll
  for (int ky = 0; ky < 3; ++ky) {
    int hh = h + ky - 1;
    if (hh < 0 || hh > 63) continue;
    #pragma unroll
    for (int kx = 0; kx < 3; ++kx) {
      int ww = w + kx - 1;
      if (ww < 0 || ww > 63) continue;
      size_t nn = ((size_t)b << 12) + (hh << 6) + ww;
      uint2 u = *(const uint2*)&Y1[nn * 256 + c0];
      float4 w4 = *(const float4*)&wT[(ky * 3 + kx) * 256 + c0];
      a0 += bf2f(u.x) * w4.x;
      a1 += bf2f(u.x >> 16) * w4.y;
      a2 += bf2f(u.y) * w4.z;
      a3 += bf2f(u.y >> 16) * w4.w;
    }
  }
  u32 p0 = (u32)f2bf(a0) | ((u32)f2bf(a1) << 16);
  u32 p1 = (u32)f2bf(a2) | ((u32)f2bf(a3) << 16);
  *(uint2*)&Yc[(size_t)n * 256 + c0] = make_uint2(p0, p1);
  float s1 = a0 + a1 + a2 + a3;
  float s2 = a0 * a0 + a1 * a1 + a2 * a2 + a3 * a3;
  #pragma unroll
  for (int off = 1; off < 64; off <<= 1) {
    s1 += __shfl_xor(s1, off);
    s2 += __shfl_xor(s2, off);
  }
  float m = s1 * (1.f / 256.f);
  float var = s2 * (1.f / 256.f) - m * m;
  float rs = rsqrtf(var + 1e-6f);
  float4 w4 = *(const float4*)&lnw[c0];
  float4 g4 = *(const float4*)&lnb[c0];
  float o0 = (a0 - m) * rs * w4.x + g4.x;
  float o1 = (a1 - m) * rs * w4.y + g4.y;
  float o2 = (a2 - m) * rs * w4.z + g4.z;
  float o3 = (a3 - m) * rs * w4.w + g4.w;
  u32 qa = (u32)f2bf(o0) | ((u32)f2bf(o1) << 16);
  u32 qb = (u32)f2bf(o2) | ((u32)f2bf(o3) << 16);
  *(uint2*)&A[(size_t)n * 256 + c0] = make_uint2(qa, qb);
}

// ------- fused ssm_in GEMM + SiLU gate, 128x128 tile (a+g panels) ----------
__global__ __launch_bounds__(256, 2)
void k_gate2(const u16* __restrict__ A, const u16* __restrict__ W,
             const float* __restrict__ bias, u16* __restrict__ G) {
  __shared__ u16 tR[2][128 * 32];
  __shared__ u16 tCa[2][128 * 32];
  __shared__ u16 tCg[2][128 * 32];
  int tid = threadIdx.x, lane = tid & 63, wv = tid >> 6;
  int wg = xcd_swz(blockIdx.x, 512);
  int rt = wg >> 2, ot = wg & 3;
  int r0 = rt * 128, o0 = ot * 128;
  int wr = wv >> 1, wc = wv & 1;
  int fr = lane & 15, kc = lane >> 4;
  const int K = 256;
  f32x4 acca[4][4] = {}, accg[4][4] = {};
  auto STAGE = [&](int buf, int kt) {
    int k0 = kt * 32;
    #pragma unroll
    for (int i = 0; i < 2; ++i) {
      int s0 = wv * 128 + i * 64;
      int s = s0 + lane;
      int row = s >> 2, off = (s & 3) * 8;
      gload16(A + (size_t)(r0 + row) * K + k0 + off, &tR[buf][s0 * 8]);
      gload16(W + (size_t)(o0 + row) * K + k0 + off, &tCa[buf][s0 * 8]);
      gload16(W + (size_t)(512 + o0 + row) * K + k0 + off, &tCg[buf][s0 * 8]);
    }
  };
  auto COMPUTE = [&](int buf) {
    bf16x8 af[4], wa[4], wgf[4];
    #pragma unroll
    for (int m = 0; m < 4; ++m)
      af[m] = *(const bf16x8*)&tR[buf][(wr * 64 + m * 16 + fr) * 32 + kc * 8];
    #pragma unroll
    for (int n = 0; n < 4; ++n) {
      wa[n]  = *(const bf16x8*)&tCa[buf][(wc * 64 + n * 16 + fr) * 32 + kc * 8];
      wgf[n] = *(const bf16x8*)&tCg[buf][(wc * 64 + n * 16 + fr) * 32 + kc * 8];
    }
    #pragma unroll
    for (int m = 0; m < 4; ++m)
      #pragma unroll
      for (int n = 0; n < 4; ++n) {
        acca[m][n] = __builtin_amdgcn_mfma_f32_16x16x32_bf16(af[m], wa[n], acca[m][n], 0, 0, 0);
        accg[m][n] = __builtin_amdgcn_mfma_f32_16x16x32_bf16(af[m], wgf[n], accg[m][n], 0, 0, 0);
      }
  };
  STAGE(0, 0);
  __syncthreads();
  int cur = 0;
  for (int kt = 0; kt < 7; ++kt) {
    STAGE(cur ^ 1, kt + 1);
    __builtin_amdgcn_sched_barrier(0);
    COMPUTE(cur);
    __syncthreads();
    cur ^= 1;
  }
  COMPUTE(cur);
  #pragma unroll
  for (int m = 0; m < 4; ++m) {
    #pragma unroll
    for (int n = 0; n < 4; ++n) {
      #pragma unroll
      for (int r = 0; r < 4; ++r) {
        int gn = r0 + wr * 64 + m * 16 + kc * 4 + r;
        int go = o0 + wc * 64 + n * 16 + fr;
        float a = acca[m][n][r] + bias[go];
        float g = accg[m][n][r] + bias[512 + go];
        G[(size_t)gn * 512 + go] = f2bf(a / (1.f + expf(-g)));
      }
    }
  }
}

// ------- FUSED: 4-dir conv1d + ssm_out GEMM + outproj GEMM + residual -------
// Stage 1 (as before): acc = Z(stencil of G) @ W3^T over K=512.
// Stage 2: M = 0.25*acc + cvec + Yc -> sM (XOR-swizzled LDS, bf16).
// Stage 3: D[o][pos] = W4 . M^T (W4 fragments straight from L2), then
//          out[(b*256+o)*4096+hw] = D + outproj_b[o] + x[idx].
__global__ __launch_bounds__(256, 2)
void k_scan_out(const u16* __restrict__ G, const u16* __restrict__ W3,
                const float* __restrict__ w02, const float* __restrict__ w14,
                const float* __restrict__ cvec, const u16* __restrict__ Yc,
                const u16* __restrict__ W4, const float* __restrict__ outb,
                const float* __restrict__ xres, float* __restrict__ out) {
  __shared__ u16 tR[2][32 * 32];
  __shared__ u16 tC[2][256 * 32];
  __shared__ u16 sM[32 * 256];
  int tid = threadIdx.x, lane = tid & 63, wv = tid >> 6;
  int wg = xcd_swz(blockIdx.x, 512);
  int r0 = wg * 32;
  int fr = lane & 15, kc = lane >> 4;
  int zrow = tid >> 3;            // 0..31
  int zg = (tid & 7) * 4;         // channel-group within the 32-wide K slice
  int n = r0 + zrow;
  int b = n >> 12, hw = n & 4095, h = hw >> 6, w = hw & 63;
  int m = w * 64 + h;
  int mm1 = m - 1, mp1 = m + 1;
  size_t o_c = (size_t)n * 512 + zg;
  size_t o_p = (size_t)(hw > 0 ? n - 1 : n) * 512 + zg;
  size_t o_n = (size_t)(hw < 4095 ? n + 1 : n) * 512 + zg;
  size_t o_u = (size_t)(m > 0 ? ((b << 12) + ((mm1 & 63) << 6) + (mm1 >> 6)) : n) * 512 + zg;
  size_t o_d = (size_t)(m < 4095 ? ((b << 12) + ((mp1 & 63) << 6) + (mp1 >> 6)) : n) * 512 + zg;
  float mP = hw > 0 ? 1.f : 0.f, mN = hw < 4095 ? 1.f : 0.f;
  float mU = m > 0 ? 1.f : 0.f, mD = m < 4095 ? 1.f : 0.f;
  f32x4 acc[2][4] = {};
  auto STAGE_C = [&](int buf, int kt) {
    int k0 = kt * 32;
    #pragma unroll
    for (int i = 0; i < 4; ++i) {
      int s0 = wv * 256 + i * 64;        // wave-uniform lane-slot base
      int s = s0 + lane;
      int row = s >> 2, off = (s & 3) * 8;
      gload16(W3 + (size_t)row * 512 + k0 + off, &tC[buf][s0 * 8]);
    }
  };
  uint2 lc, lp, ln_, lu, ld;
  float4 va, vb;
  auto ZLOAD = [&](int kt) {
    int c = kt * 32 + zg;
    lc  = *(const uint2*)&G[o_c + (kt * 32)];
    lp  = *(const uint2*)&G[o_p + (kt * 32)];
    ln_ = *(const uint2*)&G[o_n + (kt * 32)];
    lu  = *(const uint2*)&G[o_u + (kt * 32)];
    ld  = *(const uint2*)&G[o_d + (kt * 32)];
    va = *(const float4*)&w02[c];
    vb = *(const float4*)&w14[c];
  };
  auto ZSTORE = [&](int buf) {
    float s_0 = mP * bf2f(lp.x) + mN * bf2f(ln_.x) + mU * bf2f(lu.x) + mD * bf2f(ld.x);
    float s_1 = mP * bf2f(lp.x >> 16) + mN * bf2f(ln_.x >> 16) + mU * bf2f(lu.x >> 16) + mD * bf2f(ld.x >> 16);
    float s_2 = mP * bf2f(lp.y) + mN * bf2f(ln_.y) + mU * bf2f(lu.y) + mD * bf2f(ld.y);
    float s_3 = mP * bf2f(lp.y >> 16) + mN * bf2f(ln_.y >> 16) + mU * bf2f(lu.y >> 16) + mD * bf2f(ld.y >> 16);
    float z0 = va.x * s_0 + vb.x * bf2f(lc.x);
    float z1 = va.y * s_1 + vb.y * bf2f(lc.x >> 16);
    float z2 = va.z * s_2 + vb.z * bf2f(lc.y);
    float z3 = va.w * s_3 + vb.w * bf2f(lc.y >> 16);
    u32 p0 = (u32)f2bf(z0) | ((u32)f2bf(z1) << 16);
    u32 p1 = (u32)f2bf(z2) | ((u32)f2bf(z3) << 16);
    *(uint2*)&tR[buf][zrow * 32 + zg] = make_uint2(p0, p1);
  };
  auto COMPUTE = [&](int buf) {
    bf16x8 af[2], wf[4];
    #pragma unroll
    for (int mi = 0; mi < 2; ++mi)
      af[mi] = *(const bf16x8*)&tR[buf][(mi * 16 + fr) * 32 + kc * 8];
    #pragma unroll
    for (int ni = 0; ni < 4; ++ni)
      wf[ni] = *(const bf16x8*)&tC[buf][(wv * 64 + ni * 16 + fr) * 32 + kc * 8];
    #pragma unroll
    for (int mi = 0; mi < 2; ++mi)
      #pragma unroll
      for (int ni = 0; ni < 4; ++ni)
        acc[mi][ni] = __builtin_amdgcn_mfma_f32_16x16x32_bf16(af[mi], wf[ni], acc[mi][ni], 0, 0, 0);
  };
  STAGE_C(0, 0);
  ZLOAD(0);
  ZSTORE(0);
  __syncthreads();
  int cur = 0;
  for (int kt = 0; kt < 15; ++kt) {
    ZLOAD(kt + 1);              // issue early: hidden under MFMA
    STAGE_C(cur ^ 1, kt + 1);
    COMPUTE(cur);
    ZSTORE(cur ^ 1);
    __syncthreads();
    cur ^= 1;
  }
  COMPUTE(cur);
  // ---- stage 2: M tile -> sM (bf16, XOR-swizzled rows) ----
  #pragma unroll
  for (int mi = 0; mi < 2; ++mi) {
    #pragma unroll
    for (int ni = 0; ni < 4; ++ni) {
      #pragma unroll
      for (int r = 0; r < 4; ++r) {
        int row = mi * 16 + kc * 4 + r;          // 0..31
        int go = wv * 64 + ni * 16 + fr;         // 0..255
        float mval = 0.25f * acc[mi][ni][r] + cvec[go] +
                     bf2f(Yc[(size_t)(r0 + row) * 256 + go]);
        u32 ba = ((u32)(row * 512 + go * 2)) ^ ((u32)(row & 7) << 4);
        *(u16*)((char*)sM + ba) = f2bf(mval);
      }
    }
  }
  __syncthreads();
  // ---- stage 3: D[o][pos] = W4 . M^T  (K = 256) ----
  f32x4 acc2[4][2] = {};
  #pragma unroll 2
  for (int kt = 0; kt < 8; ++kt) {
    bf16x8 af2[4], bfv[2];
    #pragma unroll
    for (int mi = 0; mi < 4; ++mi)
      af2[mi] = *(const bf16x8*)&W4[(size_t)(wv * 64 + mi * 16 + fr) * 256 + kt * 32 + kc * 8];
    #pragma unroll
    for (int ni = 0; ni < 2; ++ni) {
      int pos = ni * 16 + fr;
      u32 ba = ((u32)(pos * 512 + (kt * 32 + kc * 8) * 2)) ^ ((u32)(pos & 7) << 4);
      bfv[ni] = *(const bf16x8*)((const char*)sM + ba);
    }
    #pragma unroll
    for (int mi = 0; mi < 4; ++mi)
      #pragma unroll
      for (int ni = 0; ni < 2; ++ni)
        acc2[mi][ni] = __builtin_amdgcn_mfma_f32_16x16x32_bf16(af2[mi], bfv[ni], acc2[mi][ni], 0, 0, 0);
  }
  int bb = r0 >> 12, hwb = r0 & 4095;
  #pragma unroll
  for (int mi = 0; mi < 4; ++mi) {
    #pragma unroll
    for (int ni = 0; ni < 2; ++ni) {
      #pragma unroll
      for (int r = 0; r < 4; ++r) {
        int o = wv * 64 + mi * 16 + kc * 4 + r;
        int pos = ni * 16 + fr;
        size_t idx = (((size_t)(bb * 256 + o)) << 12) + hwb + pos;
        float res = __builtin_nontemporal_load(&xres[idx]);
        __builtin_nontemporal_store(acc2[mi][ni][r] + outb[o] + res, &out[idx]);
      }
    }
  }
}

extern "C" void kernel_launch(void* const* d_in, const int* in_sizes, int n_in,
                              void* d_out, int out_size, void* d_ws, size_t ws_size,
                              hipStream_t stream) {
  const float* x         = (const float*)d_in[0];
  const float* ln2d_w    = (const float*)d_in[1];
  const float* ln2d_b    = (const float*)d_in[2];
  const float* inproj_w  = (const float*)d_in[3];
  const float* inproj_b  = (const float*)d_in[4];
  const float* dw2d_w    = (const float*)d_in[5];
  const float* dw2d_b    = (const float*)d_in[6];
  const float* ssm_ln_w  = (const float*)d_in[7];
  const float* ssm_ln_b  = (const float*)d_in[8];
  const float* ssm_in_w  = (const float*)d_in[9];
  const float* ssm_in_b  = (const float*)d_in[10];
  const float* ssm_dw_w  = (const float*)d_in[11];
  const float* ssm_dw_b  = (const float*)d_in[12];
  const float* ssm_out_w = (const float*)d_in[13];
  const float* ssm_out_b = (const float*)d_in[14];
  const float* outproj_w = (const float*)d_in[15];
  const float* outproj_b = (const float*)d_in[16];
  float* out = (float*)d_out;

  char* ws = (char*)d_ws;
  size_t off = 0;
  auto take = [&](size_t bytes) -> char* {
    char* p = ws + off;
    off = (off + bytes + 255) & ~(size_t)255;
    return p;
  };
  u16* w2b    = (u16*)take(262144 * 2);
  u16* w3b    = (u16*)take(131072 * 2);
  u16* w4b    = (u16*)take(65536 * 2);
  float* cvec = (float*)take(256 * 4);
  float* wT9  = (float*)take(9 * 256 * 4);
  float* w02  = (float*)take(512 * 4);
  float* w14  = (float*)take(512 * 4);
  u16* Abuf   = (u16*)take((size_t)16384 * 256 * 2);
  u16* Y1     = (u16*)take((size_t)16384 * 256 * 2);
  u16* Yc     = (u16*)take((size_t)16384 * 256 * 2);
  u16* G      = (u16*)take((size_t)16384 * 512 * 2);
  (void)ws_size; (void)in_sizes; (void)n_in; (void)out_size;

  // 1) LN + inproj GEMM (fused) -> Y1; prep blocks ride along
  k_lnproj<<<706, 256, 0, stream>>>(x, ln2d_w, ln2d_b, inproj_w, inproj_b, Y1,
                                    ssm_in_w, ssm_out_w, outproj_w, dw2d_w,
                                    ssm_dw_w, ssm_dw_b, ssm_out_b,
                                    w2b, w3b, w4b, cvec, wT9, w02, w14);
  // 2) depthwise 3x3 + fused ssm LN
  k_dw3x3_ln<<<4096, 256, 0, stream>>>(Y1, wT9, dw2d_b, ssm_ln_w, ssm_ln_b, Yc, Abuf);
  // 3) ssm_in GEMM + SiLU gate
  k_gate2<<<512, 256, 0, stream>>>(Abuf, w2b, ssm_in_b, G);
  // 4) fused conv1d-scan + ssm_out GEMM + outproj GEMM + residual -> out
  k_scan_out<<<512, 256, 0, stream>>>(G, w3b, w02, w14, cvec, Yc,
                                      w4b, outproj_b, x, out);
}